// Round 3
// baseline (190.347 us; speedup 1.0000x reference)
//
#include <hip/hip_runtime.h>

// Fused capsule conv + dynamic routing for MI355X (gfx950).
// x:      [8, 32, 8, 32, 32]  f32   (bs, ci, ni, hi, wi)
// conv_w: [256, 8, 3, 3]      f32   (co*no, ni, kh, kw)
// bias:   [32, 8, 1, 1]       f32
// out:    [8, 32, 8, 32, 32]  f32   (bs, co, no, ho, wo)
//
// One block per output pixel (b,h,w): 8192 blocks x 256 threads.
// votes[ci=32][col=256] kept in registers: thread t owns
//   ci in [ (t>>6)*8 , +8 ),  col in [ (t&63)*4 , +4 )  -> acc[8][4].
// Weights staged to LDS in 3 K-chunks of 24 rows, XOR-swizzled
// (w_lds[k][col ^ ((k&7)<<2)]) so the conflict-free b128 read pattern
// survives and staging writes are only ~8-way conflicted.

#define KTOT 72   // ni(8) * 3 * 3
#define KCH  24   // K-chunk rows staged per pass
#define NCH  3    // KTOT / KCH
#define COLS 256  // co(32) * no(8)
#define ITERS 3

__global__ __launch_bounds__(256, 3)
void caps_fused(const float* __restrict__ x,
                const float* __restrict__ cw,
                const float* __restrict__ bias,
                float* __restrict__ out)
{
    __shared__ float w_lds[KCH * COLS];     // 24*256*4 = 36,864 B
    __shared__ float p_lds[KTOT * 32];      // [k][ci]    9,216 B
    __shared__ float logits_lds[32 * 33];   // [ci][co]   4,224 B (padded)
    __shared__ float route_lds[32 * 33];    //            4,224 B
    __shared__ float pre_part[4 * COLS];    // [wave][col] 4,096 B
    __shared__ float act_lds[COLS];         //            1,024 B

    const int t   = threadIdx.x;
    const int bid = blockIdx.x;
    const int b   = bid >> 10;
    const int hw  = bid & 1023;
    const int h   = hw >> 5;
    const int w   = hw & 31;

    // ---- stage input patch: p_lds[k][ci] = x[b][ci][ni][h+kh-1][w+kw-1]
    #pragma unroll
    for (int i = 0; i < 9; ++i) {
        int idx = i * 256 + t;                  // 0..2303
        int k = idx >> 5, ci = idx & 31;
        int ni = k / 9, r9 = k - ni * 9;
        int kh = r9 / 3, kw = r9 - kh * 3;
        int hy = h + kh - 1, wx = w + kw - 1;
        float v = 0.0f;
        if ((unsigned)hy < 32u && (unsigned)wx < 32u)
            v = x[(((b * 32 + ci) * 8 + ni) << 10) + (hy << 5) + wx];
        p_lds[idx] = v;
    }
    // init logits to zero (covered by the first __syncthreads below)
    for (int idx = t; idx < 32 * 33; idx += 256) logits_lds[idx] = 0.0f;

    const int c4  = (t & 63) << 2;   // col base: 4 consecutive cols
    const int ci8 = (t >> 6) << 3;   // ci base: 8 rows (per wave)

    float acc[8][4];
    #pragma unroll
    for (int r = 0; r < 8; ++r)
        #pragma unroll
        for (int j = 0; j < 4; ++j) acc[r][j] = 0.0f;

    // ---- conv: votes[ci][col] = sum_k patch[ci][k] * w[col][k]
    for (int ch = 0; ch < NCH; ++ch) {
        if (ch) __syncthreads();   // previous chunk's MACs done before overwrite
        // stage weight chunk (coalesced float4 global reads)
        #pragma unroll
        for (int i = 0; i < 6; ++i) {
            int vidx = i * 256 + t;            // 0..1535
            int col = vidx / 6, kv = vidx - col * 6;
            int kl = kv << 2;
            float4 wq = *reinterpret_cast<const float4*>(cw + col * KTOT + ch * KCH + kl);
            float wa[4] = {wq.x, wq.y, wq.z, wq.w};
            #pragma unroll
            for (int u = 0; u < 4; ++u) {
                int kr = kl + u;
                w_lds[kr * COLS + (col ^ ((kr & 7) << 2))] = wa[u];
            }
        }
        __syncthreads();   // chunk (and, first time, patch + logits) visible
        #pragma unroll 8
        for (int kl = 0; kl < KCH; ++kl) {
            int kk = ch * KCH + kl;
            float4 wv = *reinterpret_cast<const float4*>(
                w_lds + kl * COLS + (c4 ^ ((kl & 7) << 2)));
            float4 a0 = *reinterpret_cast<const float4*>(p_lds + kk * 32 + ci8);
            float4 a1 = *reinterpret_cast<const float4*>(p_lds + kk * 32 + ci8 + 4);
            float av[8] = {a0.x, a0.y, a0.z, a0.w, a1.x, a1.y, a1.z, a1.w};
            float wj[4] = {wv.x, wv.y, wv.z, wv.w};
            #pragma unroll
            for (int r = 0; r < 8; ++r)
                #pragma unroll
                for (int j = 0; j < 4; ++j)
                    acc[r][j] = fmaf(av[r], wj[j], acc[r][j]);
        }
    }
    __syncthreads();

    // ---- dynamic routing (3 iterations), everything per-pixel in LDS/regs
    const float bias_t = bias[t];        // bias[co][no] with col = t
    const int ci_s = t >> 3;             // softmax: one ci row per 8 lanes
    const int j_s  = t & 7;
    const int co_t = (t & 63) >> 1;      // co of this thread's 4 cols

    for (int it = 0; it < ITERS; ++it) {
        // (a) route = softmax over co of logits[ci][:]
        float l0 = logits_lds[ci_s * 33 + j_s];
        float l1 = logits_lds[ci_s * 33 + j_s + 8];
        float l2 = logits_lds[ci_s * 33 + j_s + 16];
        float l3 = logits_lds[ci_s * 33 + j_s + 24];
        float mx = fmaxf(fmaxf(l0, l1), fmaxf(l2, l3));
        mx = fmaxf(mx, __shfl_xor(mx, 1, 8));
        mx = fmaxf(mx, __shfl_xor(mx, 2, 8));
        mx = fmaxf(mx, __shfl_xor(mx, 4, 8));
        float e0 = __expf(l0 - mx), e1 = __expf(l1 - mx);
        float e2 = __expf(l2 - mx), e3 = __expf(l3 - mx);
        float s = e0 + e1 + e2 + e3;
        s += __shfl_xor(s, 1, 8);
        s += __shfl_xor(s, 2, 8);
        s += __shfl_xor(s, 4, 8);
        float inv = 1.0f / s;
        route_lds[ci_s * 33 + j_s]      = e0 * inv;
        route_lds[ci_s * 33 + j_s + 8]  = e1 * inv;
        route_lds[ci_s * 33 + j_s + 16] = e2 * inv;
        route_lds[ci_s * 33 + j_s + 24] = e3 * inv;
        __syncthreads();

        // (b) partial preactivate: this wave's 8 ci rows, 4 cols
        float pp0 = 0.f, pp1 = 0.f, pp2 = 0.f, pp3 = 0.f;
        #pragma unroll
        for (int r = 0; r < 8; ++r) {
            float rt = route_lds[(ci8 + r) * 33 + co_t];
            pp0 = fmaf(rt, acc[r][0], pp0);
            pp1 = fmaf(rt, acc[r][1], pp1);
            pp2 = fmaf(rt, acc[r][2], pp2);
            pp3 = fmaf(rt, acc[r][3], pp3);
        }
        float4 ppv; ppv.x = pp0; ppv.y = pp1; ppv.z = pp2; ppv.w = pp3;
        *reinterpret_cast<float4*>(pre_part + ((t >> 6) << 8) + c4) = ppv;
        __syncthreads();

        // (c) reduce over the 4 waves, add bias, squash over no (8 lanes)
        float pre = bias_t + pre_part[t] + pre_part[256 + t]
                           + pre_part[512 + t] + pre_part[768 + t];
        float s2 = pre * pre;
        s2 += __shfl_xor(s2, 1, 8);
        s2 += __shfl_xor(s2, 2, 8);
        s2 += __shfl_xor(s2, 4, 8);
        float a = pre * (sqrtf(s2) / (1.0f + s2));

        if (it == ITERS - 1) {
            // out[b][co][no][h][w], col = t
            out[(((b << 8) + t) << 10) + hw] = a;
        } else {
            act_lds[t] = a;
            __syncthreads();
            // (d) distances[ci][co] = sum_no act[co][no]*votes[ci][co][no];
            //     logits += distances
            float4 av4 = *reinterpret_cast<const float4*>(act_lds + c4);
            #pragma unroll
            for (int r = 0; r < 8; ++r) {
                float d = av4.x * acc[r][0] + av4.y * acc[r][1]
                        + av4.z * acc[r][2] + av4.w * acc[r][3];
                d += __shfl_xor(d, 1);           // combine the two no-halves
                if ((t & 1) == 0)
                    logits_lds[(ci8 + r) * 33 + co_t] += d;
            }
            __syncthreads();
        }
    }
}

extern "C" void kernel_launch(void* const* d_in, const int* in_sizes, int n_in,
                              void* d_out, int out_size, void* d_ws, size_t ws_size,
                              hipStream_t stream) {
    const float* x    = (const float*)d_in[0];
    const float* cw   = (const float*)d_in[1];
    const float* bias = (const float*)d_in[2];
    float* out = (float*)d_out;
    (void)in_sizes; (void)n_in; (void)out_size; (void)d_ws; (void)ws_size;
    caps_fused<<<8192, 256, 0, stream>>>(x, cw, bias, out);
}

// Round 4
// 154.288 us; speedup vs baseline: 1.2337x; 1.2337x over previous
//
#include <hip/hip_runtime.h>

// Fused capsule conv + dynamic routing, MFMA version.
// x:      [8, 32, 8, 32, 32] f32   (bs, ci, ni, hi, wi)
// conv_w: [256, 8, 3, 3]     f32   (co*no, ni, kh, kw)
// bias:   [32, 8, 1, 1]      f32   (zeros, but honored)
// out:    [8, 32, 8, 32, 32] f32   (bs, co, no, ho, wo)
//
// Prep kernel: w_hi = bf16(conv_w) laid out [col=256][k=96] (k 72..95 zero) in d_ws.
// Main kernel: one block per pixel, 256 thr = 4 waves. Per-pixel GEMM
//   votes[32ci][256col] = A'[32][192] x B[192][256]
// via mfma_f32_16x16x32_bf16, A' = [a_hi | pad | a_lo | pad] in LDS,
// B-frags read straight from global (L2-resident 48 KB). 2-term bf16 split:
// votes ~= a_hi*w_hi + a_lo*w_hi (dropped a*w_lo ~ 2^-9 rel, << 5.6e-3 thresh).
// Wave w owns cols [w*64, w*64+64): acc[2 Mtile][4 Ntile] f32x4.
// D-layout: col = lane&15 (+16*Nt), row(ci) = (lane>>4)*4 + reg (+16*Mt).
// Routing is wave-local: ci-reduce = shfl_xor 16/32, no-reduce = shfl_xor 1/2/4.

typedef __attribute__((ext_vector_type(8))) short short8;
typedef __attribute__((ext_vector_type(4))) float f32x4;

#define LSTR 200   // A' row stride (bf16): 400 B -> frag-read banks 2-way max
#define RSTR 36    // routeT row stride (f32): 144 B, 16B-aligned rows

__device__ __forceinline__ ushort f2bf(float f) {
    unsigned u = __float_as_uint(f);
    unsigned r = (u + 0x7fffu + ((u >> 16) & 1u)) >> 16;   // RNE
    return (ushort)r;
}
__device__ __forceinline__ float bf2f(ushort h) {
    return __uint_as_float(((unsigned)h) << 16);
}

__global__ void prep_w(const float* __restrict__ cw, ushort* __restrict__ wp) {
    int e = blockIdx.x * 256 + threadIdx.x;   // 0..24575 over [col][96]
    int col = e / 96, k = e - col * 96;
    float v = (k < 72) ? cw[col * 72 + k] : 0.0f;
    wp[e] = f2bf(v);
}

__global__ __launch_bounds__(256, 4)
void caps_mfma(const float* __restrict__ x,
               const ushort* __restrict__ wp,
               const float* __restrict__ bias,
               float* __restrict__ out)
{
    __shared__ ushort A[32 * LSTR];       // 12,800 B
    __shared__ float  logits[32 * 33];    //  4,224 B  [ci][co]
    __shared__ float  routeT[32 * RSTR];  //  4,608 B  [co][ci]

    const int t   = threadIdx.x;
    const int bid = blockIdx.x;
    const int b   = bid >> 10;
    const int hw  = bid & 1023;
    const int h   = hw >> 5;
    const int w   = hw & 31;

    for (int idx = t; idx < 32 * 33; idx += 256) logits[idx] = 0.0f;

    // ---- build A' rows: thread t <-> (ci = t>>3, ni = t&7), 9 taps each
    {
        const int ci = t >> 3, ni = t & 7;
        const float* xb = x + (((size_t)((b * 32 + ci) * 8 + ni)) << 10);
        ushort* Ar = A + ci * LSTR;
        #pragma unroll
        for (int kh = 0; kh < 3; ++kh)
            #pragma unroll
            for (int kw = 0; kw < 3; ++kw) {
                int hy = h + kh - 1, wx = w + kw - 1;
                float v = 0.0f;
                if ((unsigned)hy < 32u && (unsigned)wx < 32u) v = xb[(hy << 5) + wx];
                ushort hi = f2bf(v);
                float lo = v - bf2f(hi);
                int k = ni * 9 + kh * 3 + kw;
                Ar[k]      = hi;
                Ar[96 + k] = f2bf(lo);
            }
        if (ni < 6) {            // zero K-pads 72..95 and 168..191 (8 B per thread each)
            uint2 z; z.x = 0u; z.y = 0u;
            *reinterpret_cast<uint2*>(Ar + 72  + ni * 4) = z;
            *reinterpret_cast<uint2*>(Ar + 168 + ni * 4) = z;
        }
    }
    __syncthreads();

    const int lane = t & 63, wv = t >> 6;
    const int lc = lane & 15, grp = lane >> 4;

    // ---- conv GEMM: 6 logical k-steps (3 x {hi, lo}), B-frags from global
    f32x4 acc[2][4];
    #pragma unroll
    for (int m = 0; m < 2; ++m)
        #pragma unroll
        for (int j = 0; j < 4; ++j) acc[m][j] = (f32x4){0.f, 0.f, 0.f, 0.f};

    #pragma unroll
    for (int ks = 0; ks < 3; ++ks) {
        short8 bq[4];
        #pragma unroll
        for (int j = 0; j < 4; ++j) {
            int col = wv * 64 + j * 16 + lc;
            bq[j] = *reinterpret_cast<const short8*>(wp + col * 96 + ks * 32 + grp * 8);
        }
        short8 ah[2], al[2];
        #pragma unroll
        for (int m = 0; m < 2; ++m) {
            const ushort* ar = A + (m * 16 + lc) * LSTR + ks * 32 + grp * 8;
            ah[m] = *reinterpret_cast<const short8*>(ar);
            al[m] = *reinterpret_cast<const short8*>(ar + 96);
        }
        #pragma unroll
        for (int m = 0; m < 2; ++m)
            #pragma unroll
            for (int j = 0; j < 4; ++j) {
                acc[m][j] = __builtin_amdgcn_mfma_f32_16x16x32_bf16(ah[m], bq[j], acc[m][j], 0, 0, 0);
                acc[m][j] = __builtin_amdgcn_mfma_f32_16x16x32_bf16(al[m], bq[j], acc[m][j], 0, 0, 0);
            }
    }
    __syncthreads();

    // ---- routing (3 iterations)
    float bj[4];
    #pragma unroll
    for (int j = 0; j < 4; ++j) bj[j] = bias[wv * 64 + j * 16 + lc];

    const int no = lane & 7;          // == col & 7 for all 4 of this lane's cols
    const int ci_s = t >> 3, j_s = t & 7;
    float act_[4];

    for (int it = 0; it < 3; ++it) {
        // (a) route = softmax over co; store transposed routeT[co][ci]
        float l0 = logits[ci_s * 33 + j_s];
        float l1 = logits[ci_s * 33 + j_s + 8];
        float l2 = logits[ci_s * 33 + j_s + 16];
        float l3 = logits[ci_s * 33 + j_s + 24];
        float mx = fmaxf(fmaxf(l0, l1), fmaxf(l2, l3));
        mx = fmaxf(mx, __shfl_xor(mx, 1));
        mx = fmaxf(mx, __shfl_xor(mx, 2));
        mx = fmaxf(mx, __shfl_xor(mx, 4));
        float e0 = __expf(l0 - mx), e1 = __expf(l1 - mx);
        float e2 = __expf(l2 - mx), e3 = __expf(l3 - mx);
        float s = e0 + e1 + e2 + e3;
        s += __shfl_xor(s, 1); s += __shfl_xor(s, 2); s += __shfl_xor(s, 4);
        float inv = 1.0f / s;
        routeT[(j_s)      * RSTR + ci_s] = e0 * inv;
        routeT[(j_s + 8)  * RSTR + ci_s] = e1 * inv;
        routeT[(j_s + 16) * RSTR + ci_s] = e2 * inv;
        routeT[(j_s + 24) * RSTR + ci_s] = e3 * inv;
        __syncthreads();

        // (b) preactivate (ci-reduce in-wave) + squash (no-reduce in-wave)
        #pragma unroll
        for (int j = 0; j < 4; ++j) {
            int co = (wv * 64 + j * 16 + lc) >> 3;
            f32x4 r0 = *reinterpret_cast<const f32x4*>(routeT + co * RSTR + grp * 4);
            f32x4 r1 = *reinterpret_cast<const f32x4*>(routeT + co * RSTR + 16 + grp * 4);
            float p = 0.0f;
            #pragma unroll
            for (int r = 0; r < 4; ++r) p = fmaf(r0[r], acc[0][j][r], p);
            #pragma unroll
            for (int r = 0; r < 4; ++r) p = fmaf(r1[r], acc[1][j][r], p);
            p += __shfl_xor(p, 16);
            p += __shfl_xor(p, 32);     // full sum over 32 ci, replicated in all grps
            p += bj[j];
            float s2 = p * p;
            s2 += __shfl_xor(s2, 1);
            s2 += __shfl_xor(s2, 2);
            s2 += __shfl_xor(s2, 4);    // sum over no within this co
            act_[j] = p * sqrtf(s2) / (1.0f + s2);
        }

        if (it == 2) break;

        // (c) distances: d[ci][co] = sum_no act*votes; logits += d
        #pragma unroll
        for (int j = 0; j < 4; ++j) {
            float a = act_[j];
            float d0 = acc[0][j][0] * a, d1 = acc[0][j][1] * a;
            float d2 = acc[0][j][2] * a, d3 = acc[0][j][3] * a;
            float d4 = acc[1][j][0] * a, d5 = acc[1][j][1] * a;
            float d6 = acc[1][j][2] * a, d7 = acc[1][j][3] * a;
            #pragma unroll
            for (int lvl = 1; lvl <= 4; lvl <<= 1) {   // reduce over no (lanes l&7)
                d0 += __shfl_xor(d0, lvl); d1 += __shfl_xor(d1, lvl);
                d2 += __shfl_xor(d2, lvl); d3 += __shfl_xor(d3, lvl);
                d4 += __shfl_xor(d4, lvl); d5 += __shfl_xor(d5, lvl);
                d6 += __shfl_xor(d6, lvl); d7 += __shfl_xor(d7, lvl);
            }
            // lane (no) writes its designated (ci) among the 8 this group holds
            float sel = d0;
            sel = (no == 1) ? d1 : sel;
            sel = (no == 2) ? d2 : sel;
            sel = (no == 3) ? d3 : sel;
            sel = (no == 4) ? d4 : sel;
            sel = (no == 5) ? d5 : sel;
            sel = (no == 6) ? d6 : sel;
            sel = (no == 7) ? d7 : sel;
            int ci_w = ((no >> 2) << 4) + (grp << 2) + (no & 3);
            int co   = (wv * 64 + j * 16 + lc) >> 3;
            logits[ci_w * 33 + co] += sel;   // unique (ci,co) writer per lane
        }
        __syncthreads();
    }

    // ---- output: act_ replicated over grp; grp 0 writes the wave's 64 cols
    if (grp == 0) {
        #pragma unroll
        for (int j = 0; j < 4; ++j) {
            int col = wv * 64 + j * 16 + lc;
            out[(((size_t)(b << 8) + col) << 10) + hw] = act_[j];
        }
    }
}

extern "C" void kernel_launch(void* const* d_in, const int* in_sizes, int n_in,
                              void* d_out, int out_size, void* d_ws, size_t ws_size,
                              hipStream_t stream) {
    const float* x    = (const float*)d_in[0];
    const float* cw   = (const float*)d_in[1];
    const float* bias = (const float*)d_in[2];
    float* out = (float*)d_out;
    ushort* wp = (ushort*)d_ws;           // 256*96*2 = 49,152 B
    (void)in_sizes; (void)n_in; (void)out_size; (void)ws_size;
    prep_w<<<96, 256, 0, stream>>>(cw, wp);
    caps_mfma<<<8192, 256, 0, stream>>>(x, wp, bias, out);
}

// Round 5
// 122.362 us; speedup vs baseline: 1.5556x; 1.2609x over previous
//
#include <hip/hip_runtime.h>

// Fused capsule conv + dynamic routing, MFMA version, lean routing.
// x:      [8, 32, 8, 32, 32] f32   (bs, ci, ni, hi, wi)
// conv_w: [256, 8, 3, 3]     f32   (co*no, ni, kh, kw)
// bias:   [32, 8, 1, 1]      f32
// out:    [8, 32, 8, 32, 32] f32   (bs, co, no, ho, wo)
//
// One block per pixel, 4 waves, wave owns 64 cols. Per-pixel GEMM
// votes[32ci][256col] via mfma_f32_16x16x32_bf16, 2-term truncating bf16
// split (votes ~= a_hi*w_hi + a_lo*w_hi; exact a = a_hi + a_lo in f32).
// Routing changes vs prev round:
//  - iteration 0 softmax skipped (route = 1/32 exactly when logits = 0)
//  - distance no-reduce = butterfly transpose-reduce (7 shfl vs 24)
//  - 5 barriers total (staging, it0-logits, it1-routeT, it1-logits, it2-routeT)

typedef __attribute__((ext_vector_type(8))) short short8;
typedef __attribute__((ext_vector_type(4))) float f32x4;

#define LSTR 200   // A' row stride (ushort): 400 B
#define RSTR 36    // routeT row stride (f32)

__device__ __forceinline__ ushort f2bf_rne(float f) {
    unsigned u = __float_as_uint(f);
    unsigned r = (u + 0x7fffu + ((u >> 16) & 1u)) >> 16;
    return (ushort)r;
}
__device__ __forceinline__ float bf2f(ushort h) {
    return __uint_as_float(((unsigned)h) << 16);
}

__global__ void prep_w(const float* __restrict__ cw, ushort* __restrict__ wp) {
    int e = blockIdx.x * 256 + threadIdx.x;   // [col=256][k=96]
    int col = e / 96, k = e - col * 96;
    float v = (k < 72) ? cw[col * 72 + k] : 0.0f;
    wp[e] = f2bf_rne(v);
}

__global__ __launch_bounds__(256, 6)
void caps_mfma(const float* __restrict__ x,
               const ushort* __restrict__ wp,
               const float* __restrict__ bias,
               float* __restrict__ out)
{
    __shared__ ushort A[32 * LSTR];       // 12,800 B
    __shared__ float  logits[32 * 33];    //  4,224 B  [ci][co]
    __shared__ float  routeT[32 * RSTR];  //  4,608 B  [co][ci]

    const int t   = threadIdx.x;
    const int bid = blockIdx.x;
    const int b   = bid >> 10;
    const int hw  = bid & 1023;
    const int h   = hw >> 5;
    const int w   = hw & 31;

    // ---- stage A' rows: thread t <-> (ci = t>>3, ni = t&7); truncating split
    {
        const int ci = t >> 3, ni = t & 7;
        const float* xb = x + (((size_t)((b * 32 + ci) * 8 + ni)) << 10);
        ushort* Ar = A + ci * LSTR;
        #pragma unroll
        for (int kh = 0; kh < 3; ++kh)
            #pragma unroll
            for (int kw = 0; kw < 3; ++kw) {
                int hy = h + kh - 1, wx = w + kw - 1;   // block-uniform bounds
                float v = 0.0f;
                if ((unsigned)hy < 32u && (unsigned)wx < 32u) v = xb[(hy << 5) + wx];
                unsigned u = __float_as_uint(v);
                ushort hi = (ushort)(u >> 16);          // trunc: exact split in f32
                float lo = v - bf2f(hi);
                int k = ni * 9 + kh * 3 + kw;
                Ar[k]      = hi;
                Ar[96 + k] = (ushort)(__float_as_uint(lo) >> 16);
            }
        if (ni < 6) {   // zero K-pads 72..95 and 168..191
            uint2 z; z.x = 0u; z.y = 0u;
            *reinterpret_cast<uint2*>(Ar + 72  + ni * 4) = z;
            *reinterpret_cast<uint2*>(Ar + 168 + ni * 4) = z;
        }
    }
    __syncthreads();

    const int lane = t & 63, wv = t >> 6;
    const int lc = lane & 15, grp = lane >> 4;
    const int no = lane & 7;
    const int par = (lane >> 3) & 1;

    // ---- conv GEMM: 3 k-steps x {hi, lo}; B-frags from global (L2-resident)
    f32x4 acc[2][4];
    #pragma unroll
    for (int m = 0; m < 2; ++m)
        #pragma unroll
        for (int j = 0; j < 4; ++j) acc[m][j] = (f32x4){0.f, 0.f, 0.f, 0.f};

    #pragma unroll
    for (int ks = 0; ks < 3; ++ks) {
        short8 bq[4];
        #pragma unroll
        for (int j = 0; j < 4; ++j) {
            int col = wv * 64 + j * 16 + lc;
            bq[j] = *reinterpret_cast<const short8*>(wp + col * 96 + ks * 32 + grp * 8);
        }
        short8 ah[2], al[2];
        #pragma unroll
        for (int m = 0; m < 2; ++m) {
            const ushort* ar = A + (m * 16 + lc) * LSTR + ks * 32 + grp * 8;
            ah[m] = *reinterpret_cast<const short8*>(ar);
            al[m] = *reinterpret_cast<const short8*>(ar + 96);
        }
        #pragma unroll
        for (int m = 0; m < 2; ++m)
            #pragma unroll
            for (int j = 0; j < 4; ++j) {
                acc[m][j] = __builtin_amdgcn_mfma_f32_16x16x32_bf16(ah[m], bq[j], acc[m][j], 0, 0, 0);
                acc[m][j] = __builtin_amdgcn_mfma_f32_16x16x32_bf16(al[m], bq[j], acc[m][j], 0, 0, 0);
            }
    }
    // no barrier: A-LDS is read-only from here on; routing uses other buffers

    float bj[4];
    #pragma unroll
    for (int j = 0; j < 4; ++j) bj[j] = bias[wv * 64 + j * 16 + lc];

    const int ci_s = t >> 3, j_s = t & 7;
    float act_[4];

    // ================= iteration 0: route = 1/32 exactly =================
    #pragma unroll
    for (int j = 0; j < 4; ++j) {
        float p = acc[0][j][0] + acc[0][j][1] + acc[0][j][2] + acc[0][j][3]
                + acc[1][j][0] + acc[1][j][1] + acc[1][j][2] + acc[1][j][3];
        p += __shfl_xor(p, 16);
        p += __shfl_xor(p, 32);             // sum over 32 ci, all lanes
        p = p * 0.03125f + bj[j];
        float s2 = p * p;
        s2 += __shfl_xor(s2, 1);
        s2 += __shfl_xor(s2, 2);
        s2 += __shfl_xor(s2, 4);            // sum over no
        act_[j] = p * sqrtf(s2) / (1.0f + s2);
    }
    // distances -> logits (pure write; covers all 1024 (ci,co) entries)
    #pragma unroll
    for (int j = 0; j < 4; ++j) {
        float a = act_[j];
        float d[8];
        #pragma unroll
        for (int r = 0; r < 4; ++r) { d[r] = acc[0][j][r] * a; d[4 + r] = acc[1][j][r] * a; }
        // butterfly transpose-reduce over the 8-lane no-group: lane ends with
        // the full no-sum for value-slot (no&7)
        const bool b4 = (no & 4) != 0, b2 = (no & 2) != 0, b1 = (no & 1) != 0;
        float e[4];
        #pragma unroll
        for (int k = 0; k < 4; ++k) {
            float keep = b4 ? d[k + 4] : d[k];
            float send = b4 ? d[k] : d[k + 4];
            e[k] = keep + __shfl_xor(send, 4);
        }
        float f[2];
        #pragma unroll
        for (int k = 0; k < 2; ++k) {
            float keep = b2 ? e[k + 2] : e[k];
            float send = b2 ? e[k] : e[k + 2];
            f[k] = keep + __shfl_xor(send, 2);
        }
        float keep = b1 ? f[1] : f[0];
        float send = b1 ? f[0] : f[1];
        float r = keep + __shfl_xor(send, 1);
        int ci_w = ((no >> 2) << 4) + (grp << 2) + (no & 3);
        int co   = (wv << 3) + 2 * j + par;
        logits[ci_w * 33 + co] = r;
    }
    __syncthreads();

    // ================= iterations 1 and 2 =================
    for (int it = 1; it <= 2; ++it) {
        // (a) softmax over co; store transposed routeT[co][ci]
        float l0 = logits[ci_s * 33 + j_s];
        float l1 = logits[ci_s * 33 + j_s + 8];
        float l2 = logits[ci_s * 33 + j_s + 16];
        float l3 = logits[ci_s * 33 + j_s + 24];
        float mx = fmaxf(fmaxf(l0, l1), fmaxf(l2, l3));
        mx = fmaxf(mx, __shfl_xor(mx, 1));
        mx = fmaxf(mx, __shfl_xor(mx, 2));
        mx = fmaxf(mx, __shfl_xor(mx, 4));
        float e0 = __expf(l0 - mx), e1 = __expf(l1 - mx);
        float e2 = __expf(l2 - mx), e3 = __expf(l3 - mx);
        float s = e0 + e1 + e2 + e3;
        s += __shfl_xor(s, 1); s += __shfl_xor(s, 2); s += __shfl_xor(s, 4);
        float inv = 1.0f / s;
        routeT[(j_s)      * RSTR + ci_s] = e0 * inv;
        routeT[(j_s + 8)  * RSTR + ci_s] = e1 * inv;
        routeT[(j_s + 16) * RSTR + ci_s] = e2 * inv;
        routeT[(j_s + 24) * RSTR + ci_s] = e3 * inv;
        __syncthreads();

        // (b) preactivate + squash, wave-local
        #pragma unroll
        for (int j = 0; j < 4; ++j) {
            int co = (wv << 3) + 2 * j + par;
            f32x4 r0 = *reinterpret_cast<const f32x4*>(routeT + co * RSTR + grp * 4);
            f32x4 r1 = *reinterpret_cast<const f32x4*>(routeT + co * RSTR + 16 + grp * 4);
            float p = 0.0f;
            #pragma unroll
            for (int r = 0; r < 4; ++r) p = fmaf(r0[r], acc[0][j][r], p);
            #pragma unroll
            for (int r = 0; r < 4; ++r) p = fmaf(r1[r], acc[1][j][r], p);
            p += __shfl_xor(p, 16);
            p += __shfl_xor(p, 32);
            p += bj[j];
            float s2 = p * p;
            s2 += __shfl_xor(s2, 1);
            s2 += __shfl_xor(s2, 2);
            s2 += __shfl_xor(s2, 4);
            act_[j] = p * sqrtf(s2) / (1.0f + s2);
        }
        if (it == 2) break;

        // (c) distances += (butterfly), accumulate into logits
        #pragma unroll
        for (int j = 0; j < 4; ++j) {
            float a = act_[j];
            float d[8];
            #pragma unroll
            for (int r = 0; r < 4; ++r) { d[r] = acc[0][j][r] * a; d[4 + r] = acc[1][j][r] * a; }
            const bool b4 = (no & 4) != 0, b2 = (no & 2) != 0, b1 = (no & 1) != 0;
            float e[4];
            #pragma unroll
            for (int k = 0; k < 4; ++k) {
                float keep = b4 ? d[k + 4] : d[k];
                float send = b4 ? d[k] : d[k + 4];
                e[k] = keep + __shfl_xor(send, 4);
            }
            float f[2];
            #pragma unroll
            for (int k = 0; k < 2; ++k) {
                float keep = b2 ? e[k + 2] : e[k];
                float send = b2 ? e[k] : e[k + 2];
                f[k] = keep + __shfl_xor(send, 2);
            }
            float keep = b1 ? f[1] : f[0];
            float send = b1 ? f[0] : f[1];
            float r = keep + __shfl_xor(send, 1);
            int ci_w = ((no >> 2) << 4) + (grp << 2) + (no & 3);
            int co   = (wv << 3) + 2 * j + par;
            logits[ci_w * 33 + co] += r;
        }
        __syncthreads();
    }

    // ---- output: act_ replicated over grp; grp 0 writes the wave's 64 cols
    if (grp == 0) {
        #pragma unroll
        for (int j = 0; j < 4; ++j) {
            int col = wv * 64 + j * 16 + lc;
            out[(((size_t)(b << 8) + col) << 10) + hw] = act_[j];
        }
    }
}

extern "C" void kernel_launch(void* const* d_in, const int* in_sizes, int n_in,
                              void* d_out, int out_size, void* d_ws, size_t ws_size,
                              hipStream_t stream) {
    const float* x    = (const float*)d_in[0];
    const float* cw   = (const float*)d_in[1];
    const float* bias = (const float*)d_in[2];
    float* out = (float*)d_out;
    ushort* wp = (ushort*)d_ws;           // 256*96*2 = 49,152 B
    (void)in_sizes; (void)n_in; (void)out_size; (void)ws_size;
    prep_w<<<96, 256, 0, stream>>>(cw, wp);
    caps_mfma<<<8192, 256, 0, stream>>>(x, wp, bias, out);
}